// Round 6
// baseline (100.557 us; speedup 1.0000x reference)
//
#include <hip/hip_runtime.h>
#include <stdint.h>

#define N_ROWS 65536
#define D_IN   1024
#define NBIT   64
#define LN_EPS 1e-5f

typedef __attribute__((ext_vector_type(8))) _Float16 f16x8;
typedef __attribute__((ext_vector_type(4))) float f32x4;

__device__ __forceinline__ void gload_lds16(const void* g, void* l) {
    __builtin_amdgcn_global_load_lds(
        (const __attribute__((address_space(1))) uint32_t*)g,
        (__attribute__((address_space(3))) uint32_t*)l, 16, 0, 0);
}

__device__ __forceinline__ f32x4 ntload4(const float* p) {
    return __builtin_nontemporal_load((const f32x4*)p);
}

__device__ __forceinline__ f32x4 mfma16(f16x8 a, f16x8 b, f32x4 c) {
    return __builtin_amdgcn_mfma_f32_16x16x32_f16(a, b, c, 0, 0, 0);
}

// one 16x16x32 K-step: split-fp16 A from 8 fp32, B hi/lo from LDS
__device__ __forceinline__ void do_tstep(f32x4 x0, f32x4 x1,
        const _Float16* bhp, f32x4* acc_h, f32x4* acc_m, f32x4* acc_ll,
        float& sum, float& sumsq) {
    float xs[8] = {x0[0], x0[1], x0[2], x0[3], x1[0], x1[1], x1[2], x1[3]};
    f16x8 ahi, alo;
#pragma unroll
    for (int j = 0; j < 8; ++j) {
        float xv = xs[j];
        sum += xv;
        sumsq = fmaf(xv, xv, sumsq);
        _Float16 h = (_Float16)xv;
        ahi[j] = h;
        alo[j] = (_Float16)((xv - (float)h) * 2048.0f);
    }
#pragma unroll
    for (int nt = 0; nt < 4; ++nt) {
        f16x8 bh = *(const f16x8*)(bhp + nt * 512);
        f16x8 bl = *(const f16x8*)(bhp + 4096 + nt * 512);
        acc_h[nt]  = mfma16(ahi, bh, acc_h[nt]);
        acc_m[nt]  = mfma16(ahi, bl, acc_m[nt]);
        acc_m[nt]  = mfma16(alo, bh, acc_m[nt]);
        acc_ll[nt] = mfma16(alo, bl, acc_ll[nt]);
    }
}

// ---------------- kernel 0: prep split-W fragments + per-bit constants ----------------
__global__ void prep_kernel(const float* __restrict__ W, const float* __restrict__ bias,
                            const float* __restrict__ g1, const float* __restrict__ b1,
                            _Float16* __restrict__ whi, _Float16* __restrict__ wlo,
                            float* __restrict__ u, float* __restrict__ v) {
    int bit = blockIdx.x;            // 0..63
    int t   = threadIdx.x;           // 0..255
    int nt  = bit >> 4, bl = bit & 15;
    float su = 0.f, sv = 0.f;
    for (int d = t; d < D_IN; d += 256) {
        float w  = W[bit * D_IN + d];
        float gw = w * g1[d];
        su += gw;
        sv += w * b1[d];
        int kt = d >> 5, gg = (d >> 3) & 3, j = d & 7;
        size_t idx = (((size_t)(kt * 4 + nt)) * 64 + gg * 16 + bl) * 8 + j;
        _Float16 h = (_Float16)gw;
        whi[idx] = h;
        wlo[idx] = (_Float16)((gw - (float)h) * 2048.0f);
    }
    __shared__ float s1[256], s2[256];
    s1[t] = su; s2[t] = sv;
    __syncthreads();
    for (int off = 128; off > 0; off >>= 1) {
        if (t < off) { s1[t] += s1[t + off]; s2[t] += s2[t + off]; }
        __syncthreads();
    }
    if (t == 0) { u[bit] = s1[0]; v[bit] = s2[0] + bias[bit]; }
}

// ---------------- kernel 1: fused LN1 + split-fp16 GEMM + LN2 + partial col sums ----------------
// 256 rows/block (16 waves, 1024 threads), grid = 256 = 1 block/CU:
// each CU reads the 256 KiB W fragment set exactly ONCE (was 4x per CU + L2 thrash).
// X read with non-temporal loads so the once-read stream doesn't evict W from L2.
__global__ void __launch_bounds__(1024) main_kernel(
        const float* __restrict__ X,
        const _Float16* __restrict__ whi, const _Float16* __restrict__ wlo,
        const float* __restrict__ u, const float* __restrict__ v,
        const float* __restrict__ g2, const float* __restrict__ b2,
        float* __restrict__ L, float* __restrict__ P) {
    __shared__ _Float16 lw[2][8192];   // [buf][hi:0..4096 | lo:4096..8192] shorts
    int tid  = threadIdx.x;
    int wid  = tid >> 6, lane = tid & 63;   // wid 0..15
    int g    = lane >> 4, r16 = lane & 15;
    int row_base = blockIdx.x * 256 + wid * 16;

    const float* xrow = X + (size_t)(row_base + r16) * D_IN + g * 8;

    // W staging: wave wid stages 1 KiB of each 16 KiB chunk.
    // wid 0..7 -> hi half segment wid; wid 8..15 -> lo half segment wid-8.
    const _Float16* gsrc = ((wid & 8) ? wlo : whi) + (wid & 7) * 512 + (size_t)lane * 8;
    const int ldst = ((wid & 8) ? 4096 : 0) + (wid & 7) * 512;   // wave-uniform (shorts)

#define STAGEW(cc, buf) gload_lds16(gsrc + (size_t)(cc) * 4096, &lw[buf][ldst])

    f32x4 acc_h0[4], acc_h1[4], acc_m[4], acc_ll[4];
#pragma unroll
    for (int nt = 0; nt < 4; ++nt) {
        acc_h0[nt] = (f32x4){0.f, 0.f, 0.f, 0.f};
        acc_h1[nt] = (f32x4){0.f, 0.f, 0.f, 0.f};
        acc_m[nt]  = (f32x4){0.f, 0.f, 0.f, 0.f};
        acc_ll[nt] = (f32x4){0.f, 0.f, 0.f, 0.f};
    }
    float sum = 0.f, sumsq = 0.f;

    STAGEW(0, 0);
    __syncthreads();   // vmcnt(0) drain: chunk 0 staged

    for (int c = 0; c < 16; ++c) {
        if (c < 15) STAGEW(c + 1, (c + 1) & 1);
        int t = c * 2;
        // load both t-steps' X up front (32 B/lane x2), non-temporal
        f32x4 x00 = ntload4(xrow + t * 32);
        f32x4 x01 = ntload4(xrow + t * 32 + 4);
        f32x4 x10 = ntload4(xrow + t * 32 + 32);
        f32x4 x11 = ntload4(xrow + t * 32 + 36);
        const _Float16* bhp = &lw[c & 1][0] + lane * 8;
        do_tstep(x00, x01, bhp,        acc_h0, acc_m, acc_ll, sum, sumsq);
        do_tstep(x10, x11, bhp + 2048, acc_h1, acc_m, acc_ll, sum, sumsq);
        __syncthreads();   // drains vmcnt(0): next chunk staged; cur buffer free
    }

    // LN1 stats: reduce over the 4 lane-groups sharing a row (xor 16,32)
    sum   += __shfl_xor(sum, 16);   sum   += __shfl_xor(sum, 32);
    sumsq += __shfl_xor(sumsq, 16); sumsq += __shfl_xor(sumsq, 32);
    float mu   = sum * (1.f / 1024.f);
    float var  = sumsq * (1.f / 1024.f) - mu * mu;
    float rstd = rsqrtf(var + LN_EPS);

    float uv[4], vv[4], g2v[4], b2v[4];
#pragma unroll
    for (int nt = 0; nt < 4; ++nt) {
        int bitc = nt * 16 + r16;
        uv[nt] = u[bitc]; vv[nt] = v[bitc]; g2v[nt] = g2[bitc]; b2v[nt] = b2[bitc];
    }
    float mu_m[4], rs_m[4];
#pragma unroll
    for (int reg = 0; reg < 4; ++reg) {
        int m = g * 4 + reg;
        mu_m[reg] = __shfl(mu, m);
        rs_m[reg] = __shfl(rstd, m);
    }

    float lg[4][4];  // [nt][reg]
#pragma unroll
    for (int nt = 0; nt < 4; ++nt)
#pragma unroll
        for (int reg = 0; reg < 4; ++reg) {
            float dot = (acc_h0[nt][reg] + acc_h1[nt][reg])
                      + acc_m[nt][reg] * (1.0f / 2048.0f)
                      + acc_ll[nt][reg] * (1.0f / 4194304.0f);
            lg[nt][reg] = rs_m[reg] * dot - rs_m[reg] * mu_m[reg] * uv[nt] + vv[nt];
        }

    // LN2 over the 64 bits of each row
#pragma unroll
    for (int reg = 0; reg < 4; ++reg) {
        float s1 = lg[0][reg] + lg[1][reg] + lg[2][reg] + lg[3][reg];
        float s2 = lg[0][reg]*lg[0][reg] + lg[1][reg]*lg[1][reg]
                 + lg[2][reg]*lg[2][reg] + lg[3][reg]*lg[3][reg];
#pragma unroll
        for (int m = 1; m <= 8; m <<= 1) {
            s1 += __shfl_xor(s1, m);
            s2 += __shfl_xor(s2, m);
        }
        float mean = s1 * (1.f / 64.f);
        float va   = s2 * (1.f / 64.f) - mean * mean;
        float rs2  = rsqrtf(va + LN_EPS);
#pragma unroll
        for (int nt = 0; nt < 4; ++nt)
            lg[nt][reg] = (lg[nt][reg] - mean) * rs2 * g2v[nt] + b2v[nt];
    }

    // store LN2'd logits (non-temporal: read once much later by final_kernel)
#pragma unroll
    for (int reg = 0; reg < 4; ++reg) {
        size_t row = (size_t)(row_base + g * 4 + reg);
#pragma unroll
        for (int nt = 0; nt < 4; ++nt)
            __builtin_nontemporal_store(lg[nt][reg], &L[row * 64 + nt * 16 + r16]);
    }

    // per-wave column partial sums, transposed layout P[bit][4096]
#pragma unroll
    for (int nt = 0; nt < 4; ++nt) {
        float cs = lg[nt][0] + lg[nt][1] + lg[nt][2] + lg[nt][3];
        cs += __shfl_xor(cs, 16);
        cs += __shfl_xor(cs, 32);
        if (g == 0)
            P[(size_t)(nt * 16 + r16) * 4096 + blockIdx.x * 16 + wid] = cs;
    }
#undef STAGEW
}

// ---------------- kernel 2: reduce column partials -> column means ----------------
__global__ void reduce_kernel(const float* __restrict__ P, float* __restrict__ cm) {
    int bit = blockIdx.x, t = threadIdx.x;
    float s = 0.f;
    for (int p = t; p < 4096; p += 256) s += P[(size_t)bit * 4096 + p];
    __shared__ float sh[256];
    sh[t] = s;
    __syncthreads();
    for (int off = 128; off > 0; off >>= 1) {
        if (t < off) sh[t] += sh[t + off];
        __syncthreads();
    }
    if (t == 0) cm[bit] = sh[0] * (1.f / (float)N_ROWS);
}

// ---------------- kernel 3: mean-center + tanh + binarize ----------------
// L lives in the B-half of d_out; each element is read once then overwritten
// by the same thread in the same iteration (deterministic, replay-safe).
__global__ void final_kernel(const float* __restrict__ L, const float* __restrict__ cm,
                             float* __restrict__ out) {
    __shared__ float cms[64];
    if (threadIdx.x < 64) cms[threadIdx.x] = cm[threadIdx.x];
    __syncthreads();
    const f32x4* L4 = (const f32x4*)L;
    f32x4* H4 = (f32x4*)out;
    f32x4* B4 = (f32x4*)(out + (size_t)N_ROWS * NBIT);
    int total = N_ROWS * NBIT / 4;
    for (int i = blockIdx.x * blockDim.x + threadIdx.x; i < total;
         i += gridDim.x * blockDim.x) {
        f32x4 x = __builtin_nontemporal_load(&L4[i]);
        int bb = (i & 15) * 4;
        f32x4 h, bo;
#pragma unroll
        for (int j = 0; j < 4; ++j) {
            h[j]  = tanhf(0.5f * (x[j] - cms[bb + j]));
            bo[j] = h[j] >= 0.f ? 1.f : -1.f;
        }
        __builtin_nontemporal_store(h, &H4[i]);
        __builtin_nontemporal_store(bo, &B4[i]);
    }
}

extern "C" void kernel_launch(void* const* d_in, const int* in_sizes, int n_in,
                              void* d_out, int out_size, void* d_ws, size_t ws_size,
                              hipStream_t stream) {
    (void)in_sizes; (void)n_in; (void)out_size; (void)ws_size;
    const float* X  = (const float*)d_in[0];
    const float* W  = (const float*)d_in[1];
    const float* bb = (const float*)d_in[2];
    const float* g1 = (const float*)d_in[3];
    const float* b1 = (const float*)d_in[4];
    const float* g2 = (const float*)d_in[5];
    const float* b2 = (const float*)d_in[6];

    char* ws = (char*)d_ws;
    _Float16* whi = (_Float16*)ws;                 // 128 KiB
    _Float16* wlo = (_Float16*)(ws + 131072);      // 128 KiB
    float* u  = (float*)(ws + 262144);             // 256 B
    float* v  = (float*)(ws + 266240);             // 256 B
    float* P  = (float*)(ws + 270336);             // 1 MiB (64*4096*4)
    float* cm = (float*)(ws + 270336 + 64 * 4096 * 4);

    float* out = (float*)d_out;
    float* L   = out + (size_t)N_ROWS * NBIT;      // reuse B-half of d_out as logit scratch

    prep_kernel<<<64, 256, 0, stream>>>(W, bb, g1, b1, whi, wlo, u, v);
    main_kernel<<<256, 1024, 0, stream>>>(X, whi, wlo, u, v, g2, b2, L, P);
    reduce_kernel<<<64, 256, 0, stream>>>(P, cm);
    final_kernel<<<2048, 256, 0, stream>>>(L, cm, out);
}

// Round 7
// 91.872 us; speedup vs baseline: 1.0945x; 1.0945x over previous
//
#include <hip/hip_runtime.h>
#include <stdint.h>

#define N_ROWS 65536
#define D_IN   1024
#define NBIT   64
#define LN_EPS 1e-5f

typedef __attribute__((ext_vector_type(8))) _Float16 f16x8;
typedef __attribute__((ext_vector_type(4))) float f32x4;

__device__ __forceinline__ void gload_lds16(const void* g, void* l) {
    __builtin_amdgcn_global_load_lds(
        (const __attribute__((address_space(1))) uint32_t*)g,
        (__attribute__((address_space(3))) uint32_t*)l, 16, 0, 0);
}

__device__ __forceinline__ f32x4 mfma16(f16x8 a, f16x8 b, f32x4 c) {
    return __builtin_amdgcn_mfma_f32_16x16x32_f16(a, b, c, 0, 0, 0);
}

// one 16x16x32 K-step: split-fp16 A from 8 fp32, B hi/lo from LDS (lo at +8192 shorts)
__device__ __forceinline__ void do_tstep(f32x4 x0, f32x4 x1,
        const _Float16* bhp, f32x4* acc_h, f32x4* acc_m, f32x4* acc_ll,
        float& sum, float& sumsq) {
    float xs[8] = {x0[0], x0[1], x0[2], x0[3], x1[0], x1[1], x1[2], x1[3]};
    f16x8 ahi, alo;
#pragma unroll
    for (int j = 0; j < 8; ++j) {
        float xv = xs[j];
        sum += xv;
        sumsq = fmaf(xv, xv, sumsq);
        _Float16 h = (_Float16)xv;
        ahi[j] = h;
        alo[j] = (_Float16)((xv - (float)h) * 2048.0f);
    }
#pragma unroll
    for (int nt = 0; nt < 4; ++nt) {
        f16x8 bh = *(const f16x8*)(bhp + nt * 512);
        f16x8 bl = *(const f16x8*)(bhp + 8192 + nt * 512);
        acc_h[nt]  = mfma16(ahi, bh, acc_h[nt]);
        acc_m[nt]  = mfma16(ahi, bl, acc_m[nt]);
        acc_m[nt]  = mfma16(alo, bh, acc_m[nt]);
        acc_ll[nt] = mfma16(alo, bl, acc_ll[nt]);
    }
}

// ---------------- kernel 0: prep split-W fragments + per-bit constants ----------------
__global__ void prep_kernel(const float* __restrict__ W, const float* __restrict__ bias,
                            const float* __restrict__ g1, const float* __restrict__ b1,
                            _Float16* __restrict__ whi, _Float16* __restrict__ wlo,
                            float* __restrict__ u, float* __restrict__ v) {
    int bit = blockIdx.x;            // 0..63
    int t   = threadIdx.x;           // 0..255
    int nt  = bit >> 4, bl = bit & 15;
    float su = 0.f, sv = 0.f;
    for (int d = t; d < D_IN; d += 256) {
        float w  = W[bit * D_IN + d];
        float gw = w * g1[d];
        su += gw;
        sv += w * b1[d];
        int kt = d >> 5, gg = (d >> 3) & 3, j = d & 7;
        size_t idx = (((size_t)(kt * 4 + nt)) * 64 + gg * 16 + bl) * 8 + j;
        _Float16 h = (_Float16)gw;
        whi[idx] = h;
        wlo[idx] = (_Float16)((gw - (float)h) * 2048.0f);
    }
    __shared__ float s1[256], s2[256];
    s1[t] = su; s2[t] = sv;
    __syncthreads();
    for (int off = 128; off > 0; off >>= 1) {
        if (t < off) { s1[t] += s1[t + off]; s2[t] += s2[t + off]; }
        __syncthreads();
    }
    if (t == 0) { u[bit] = s1[0]; v[bit] = s2[0] + bias[bit]; }
}

// ---------------- kernel 1: fused LN1 + split-fp16 GEMM + LN2 + partial col sums ----------------
// BK=128 (4 t-steps/chunk, 8 chunks): X read in 512-B contiguous runs per row-visit
// (2x DRAM page locality vs BK=64). W chunk 32 KiB double-buffered (64 KiB LDS,
// 2 blocks/CU). 4 waves/block, 64 rows/block, grid = 1024.
__global__ void __launch_bounds__(256) main_kernel(
        const float* __restrict__ X,
        const _Float16* __restrict__ whi, const _Float16* __restrict__ wlo,
        const float* __restrict__ u, const float* __restrict__ v,
        const float* __restrict__ g2, const float* __restrict__ b2,
        float* __restrict__ L, float* __restrict__ P) {
    __shared__ _Float16 lw[2][16384];   // [buf][hi:0..8192 | lo:8192..16384] shorts
    int tid  = threadIdx.x;
    int wid  = tid >> 6, lane = tid & 63;
    int g    = lane >> 4, r16 = lane & 15;
    int row_base = blockIdx.x * 64 + wid * 16;

    const float* xrow = X + (size_t)(row_base + r16) * D_IN + g * 8;

    // staging map: waves 0,1 stage the 16 KiB hi block; waves 2,3 the lo block.
    // each wave: 8 KiB = 8 x (1 KiB wave-load), linear copy (global layout == LDS layout)
    const _Float16* gsrc = ((wid & 2) ? wlo : whi) + (wid & 1) * 4096 + (size_t)lane * 8;
    const int ldst = ((wid & 2) ? 8192 : 0) + (wid & 1) * 4096;   // shorts, wave-uniform

#define STAGEW(cc, buf) do {                                                  \
        const _Float16* gs_ = gsrc + (size_t)(cc) * 8192;                     \
        _Float16* ld_ = &lw[buf][ldst];                                       \
        _Pragma("unroll")                                                     \
        for (int r = 0; r < 8; ++r)                                           \
            gload_lds16(gs_ + r * 512, ld_ + r * 512);                        \
    } while (0)

    f32x4 acc_h0[4], acc_h1[4], acc_m[4], acc_ll[4];
#pragma unroll
    for (int nt = 0; nt < 4; ++nt) {
        acc_h0[nt] = (f32x4){0.f, 0.f, 0.f, 0.f};
        acc_h1[nt] = (f32x4){0.f, 0.f, 0.f, 0.f};
        acc_m[nt]  = (f32x4){0.f, 0.f, 0.f, 0.f};
        acc_ll[nt] = (f32x4){0.f, 0.f, 0.f, 0.f};
    }
    float sum = 0.f, sumsq = 0.f;

    STAGEW(0, 0);
    __syncthreads();   // vmcnt(0) drain: chunk 0 staged

    for (int c = 0; c < 8; ++c) {
        if (c < 7) STAGEW(c + 1, (c + 1) & 1);
        // issue the full 512-B-per-row X window for this chunk (8 x float4/lane)
        const float* xp = xrow + c * 128;
        f32x4 xv[8];
#pragma unroll
        for (int t2 = 0; t2 < 4; ++t2) {
            xv[2 * t2]     = *(const f32x4*)(xp + t2 * 32);
            xv[2 * t2 + 1] = *(const f32x4*)(xp + t2 * 32 + 4);
        }
        const _Float16* bhp = &lw[c & 1][0] + lane * 8;
#pragma unroll
        for (int t2 = 0; t2 < 4; ++t2) {
            do_tstep(xv[2 * t2], xv[2 * t2 + 1], bhp + t2 * 2048,
                     (t2 & 1) ? acc_h1 : acc_h0, acc_m, acc_ll, sum, sumsq);
        }
        __syncthreads();   // drains vmcnt(0): next chunk staged; cur buffer free
    }

    // LN1 stats: reduce over the 4 lane-groups sharing a row (xor 16,32)
    sum   += __shfl_xor(sum, 16);   sum   += __shfl_xor(sum, 32);
    sumsq += __shfl_xor(sumsq, 16); sumsq += __shfl_xor(sumsq, 32);
    float mu   = sum * (1.f / 1024.f);
    float var  = sumsq * (1.f / 1024.f) - mu * mu;
    float rstd = rsqrtf(var + LN_EPS);

    float uv[4], vv[4], g2v[4], b2v[4];
#pragma unroll
    for (int nt = 0; nt < 4; ++nt) {
        int bitc = nt * 16 + r16;
        uv[nt] = u[bitc]; vv[nt] = v[bitc]; g2v[nt] = g2[bitc]; b2v[nt] = b2[bitc];
    }
    float mu_m[4], rs_m[4];
#pragma unroll
    for (int reg = 0; reg < 4; ++reg) {
        int m = g * 4 + reg;
        mu_m[reg] = __shfl(mu, m);
        rs_m[reg] = __shfl(rstd, m);
    }

    float lg[4][4];  // [nt][reg]
#pragma unroll
    for (int nt = 0; nt < 4; ++nt)
#pragma unroll
        for (int reg = 0; reg < 4; ++reg) {
            float dot = (acc_h0[nt][reg] + acc_h1[nt][reg])
                      + acc_m[nt][reg] * (1.0f / 2048.0f)
                      + acc_ll[nt][reg] * (1.0f / 4194304.0f);
            lg[nt][reg] = rs_m[reg] * dot - rs_m[reg] * mu_m[reg] * uv[nt] + vv[nt];
        }

    // LN2 over the 64 bits of each row
#pragma unroll
    for (int reg = 0; reg < 4; ++reg) {
        float s1 = lg[0][reg] + lg[1][reg] + lg[2][reg] + lg[3][reg];
        float s2 = lg[0][reg]*lg[0][reg] + lg[1][reg]*lg[1][reg]
                 + lg[2][reg]*lg[2][reg] + lg[3][reg]*lg[3][reg];
#pragma unroll
        for (int m = 1; m <= 8; m <<= 1) {
            s1 += __shfl_xor(s1, m);
            s2 += __shfl_xor(s2, m);
        }
        float mean = s1 * (1.f / 64.f);
        float va   = s2 * (1.f / 64.f) - mean * mean;
        float rs2  = rsqrtf(va + LN_EPS);
#pragma unroll
        for (int nt = 0; nt < 4; ++nt)
            lg[nt][reg] = (lg[nt][reg] - mean) * rs2 * g2v[nt] + b2v[nt];
    }

    // store LN2'd logits (cacheable: 16 MiB stays L3-resident for final_kernel)
#pragma unroll
    for (int reg = 0; reg < 4; ++reg) {
        size_t row = (size_t)(row_base + g * 4 + reg);
#pragma unroll
        for (int nt = 0; nt < 4; ++nt)
            L[row * 64 + nt * 16 + r16] = lg[nt][reg];
    }

    // per-wave column partial sums, transposed layout P[bit][4096]
#pragma unroll
    for (int nt = 0; nt < 4; ++nt) {
        float cs = lg[nt][0] + lg[nt][1] + lg[nt][2] + lg[nt][3];
        cs += __shfl_xor(cs, 16);
        cs += __shfl_xor(cs, 32);
        if (g == 0)
            P[(size_t)(nt * 16 + r16) * 4096 + blockIdx.x * 4 + wid] = cs;
    }
#undef STAGEW
}

// ---------------- kernel 2: reduce column partials -> column means ----------------
__global__ void reduce_kernel(const float* __restrict__ P, float* __restrict__ cm) {
    int bit = blockIdx.x, t = threadIdx.x;
    float s = 0.f;
    for (int p = t; p < 4096; p += 256) s += P[(size_t)bit * 4096 + p];
    __shared__ float sh[256];
    sh[t] = s;
    __syncthreads();
    for (int off = 128; off > 0; off >>= 1) {
        if (t < off) sh[t] += sh[t + off];
        __syncthreads();
    }
    if (t == 0) cm[bit] = sh[0] * (1.f / (float)N_ROWS);
}

// ---------------- kernel 3: mean-center + fast sign-exact tanh + binarize ----------------
// tanh approx: |y|<0.5 -> odd polynomial (sign-exact by construction, |err|<4e-4);
// else 1 - 2/(e^{2y}+1) (|value|>0.46, sign trivially exact). Threshold is 0.02.
__global__ void final_kernel(const float* __restrict__ L, const float* __restrict__ cm,
                             float* __restrict__ out) {
    __shared__ float cms[64];
    if (threadIdx.x < 64) cms[threadIdx.x] = cm[threadIdx.x];
    __syncthreads();
    const f32x4* L4 = (const f32x4*)L;
    f32x4* H4 = (f32x4*)out;
    f32x4* B4 = (f32x4*)(out + (size_t)N_ROWS * NBIT);
    int total = N_ROWS * NBIT / 4;
    for (int i = blockIdx.x * blockDim.x + threadIdx.x; i < total;
         i += gridDim.x * blockDim.x) {
        f32x4 x = L4[i];
        int bb = (i & 15) * 4;
        f32x4 h, bo;
#pragma unroll
        for (int j = 0; j < 4; ++j) {
            float y  = 0.5f * (x[j] - cms[bb + j]);
            float y2 = y * y;
            float poly = y * fmaf(y2, fmaf(y2, 2.f / 15.f, -1.f / 3.f), 1.f);
            float e  = __expf(2.f * y);
            float ef = 1.f - 2.f / (e + 1.f);
            float hv = (fabsf(y) < 0.5f) ? poly : ef;
            h[j]  = hv;
            bo[j] = hv >= 0.f ? 1.f : -1.f;
        }
        __builtin_nontemporal_store(h, &H4[i]);
        __builtin_nontemporal_store(bo, &B4[i]);
    }
}

extern "C" void kernel_launch(void* const* d_in, const int* in_sizes, int n_in,
                              void* d_out, int out_size, void* d_ws, size_t ws_size,
                              hipStream_t stream) {
    (void)in_sizes; (void)n_in; (void)out_size; (void)ws_size;
    const float* X  = (const float*)d_in[0];
    const float* W  = (const float*)d_in[1];
    const float* bb = (const float*)d_in[2];
    const float* g1 = (const float*)d_in[3];
    const float* b1 = (const float*)d_in[4];
    const float* g2 = (const float*)d_in[5];
    const float* b2 = (const float*)d_in[6];

    char* ws = (char*)d_ws;
    _Float16* whi = (_Float16*)ws;                 // 128 KiB
    _Float16* wlo = (_Float16*)(ws + 131072);      // 128 KiB
    float* u  = (float*)(ws + 262144);             // 256 B
    float* v  = (float*)(ws + 266240);             // 256 B
    float* P  = (float*)(ws + 270336);             // 1 MiB (64*4096*4)
    float* cm = (float*)(ws + 270336 + 64 * 4096 * 4);

    float* out = (float*)d_out;
    float* L   = out + (size_t)N_ROWS * NBIT;      // reuse B-half of d_out as logit scratch

    prep_kernel<<<64, 256, 0, stream>>>(W, bb, g1, b1, whi, wlo, u, v);
    main_kernel<<<1024, 256, 0, stream>>>(X, whi, wlo, u, v, g2, b2, L, P);
    reduce_kernel<<<64, 256, 0, stream>>>(P, cm);
    final_kernel<<<2048, 256, 0, stream>>>(L, cm, out);
}

// Round 8
// 84.387 us; speedup vs baseline: 1.1916x; 1.0887x over previous
//
#include <hip/hip_runtime.h>
#include <stdint.h>

#define N_ROWS 65536
#define D_IN   1024
#define NBIT   64
#define LN_EPS 1e-5f

typedef __attribute__((ext_vector_type(8)))  _Float16 f16x8;
typedef __attribute__((ext_vector_type(4)))  float f32x4;
typedef __attribute__((ext_vector_type(16))) float f32x16;

__device__ __forceinline__ void gload_lds16(const void* g, void* l) {
    __builtin_amdgcn_global_load_lds(
        (const __attribute__((address_space(1))) uint32_t*)g,
        (__attribute__((address_space(3))) uint32_t*)l, 16, 0, 0);
}

__device__ __forceinline__ f32x16 mfma32(f16x8 a, f16x8 b, f32x16 c) {
    return __builtin_amdgcn_mfma_f32_32x32x16_f16(a, b, c, 0, 0, 0);
}

// ---------------- kernel 0: prep split-W fragments + per-bit constants ----------------
// 32x32x16 B-fragment layout, chunk-major (BK=128 => 8 t-steps/chunk, 8 chunks):
//   n(bit) = nt*32 + (lane&31),  k = chunk*128 + t*16 + (lane>>5)*8 + j
//   idx = chunk*8192 + t*1024 + nt*512 + lane*8 + j        (shorts, per hi/lo array)
// whi = fp16(gw); wlo = fp16((gw - whi)*2048)  [exact split, lo scaled to stay normal]
__global__ void prep_kernel(const float* __restrict__ W, const float* __restrict__ bias,
                            const float* __restrict__ g1, const float* __restrict__ b1,
                            _Float16* __restrict__ whi, _Float16* __restrict__ wlo,
                            float* __restrict__ u, float* __restrict__ v) {
    int bit = blockIdx.x;            // 0..63
    int t   = threadIdx.x;           // 0..255
    int nt  = bit >> 5, col = bit & 31;
    float su = 0.f, sv = 0.f;
    for (int d = t; d < D_IN; d += 256) {
        float w  = W[bit * D_IN + d];
        float gw = w * g1[d];
        su += gw;
        sv += w * b1[d];
        int tg = d >> 4, c = tg >> 3, tt = tg & 7;
        int hi = (d >> 3) & 1, j = d & 7;
        int lane = col + 32 * hi;
        size_t idx = (size_t)c * 8192 + tt * 1024 + nt * 512 + lane * 8 + j;
        _Float16 h = (_Float16)gw;
        whi[idx] = h;
        wlo[idx] = (_Float16)((gw - (float)h) * 2048.0f);
    }
    __shared__ float s1[256], s2[256];
    s1[t] = su; s2[t] = sv;
    __syncthreads();
    for (int off = 128; off > 0; off >>= 1) {
        if (t < off) { s1[t] += s1[t + off]; s2[t] += s2[t + off]; }
        __syncthreads();
    }
    if (t == 0) { u[bit] = s1[0]; v[bit] = s2[0] + bias[bit]; }
}

// ---------------- kernel 1: fused LN1 + split-fp16 32x32 GEMM + LN2 + partials ----------------
// 4 waves x 32 rows = 128 rows/block, grid 512 (2 blocks/CU, all resident).
// BK=128, W chunk 32 KiB double-buffered (64 KiB LDS). Each B-fragment LDS read is
// amortized over 32 rows (2x the 16x16 scheme) -> W-LDS traffic per CU halves.
__global__ void __launch_bounds__(256, 2) main_kernel(
        const float* __restrict__ X,
        const _Float16* __restrict__ whi, const _Float16* __restrict__ wlo,
        const float* __restrict__ u, const float* __restrict__ v,
        const float* __restrict__ g2, const float* __restrict__ b2,
        float* __restrict__ L, float* __restrict__ P) {
    __shared__ _Float16 lw[2][16384];   // [buf][hi:0..8192 | lo:8192..16384] shorts
    int tid  = threadIdx.x;
    int wid  = tid >> 6, lane = tid & 63;
    int col  = lane & 31, hi = lane >> 5;
    int row_base = blockIdx.x * 128 + wid * 32;

    const float* xrow = X + (size_t)(row_base + col) * D_IN + hi * 8;

    // staging: waves 0,1 -> hi halves; waves 2,3 -> lo halves (8 KiB each, linear)
    const _Float16* gsrc = ((wid & 2) ? wlo : whi) + (wid & 1) * 4096 + (size_t)lane * 8;
    const int ldst = ((wid & 2) ? 8192 : 0) + (wid & 1) * 4096;   // shorts, wave-uniform

#define STAGEW(cc, buf) do {                                                  \
        const _Float16* gs_ = gsrc + (size_t)(cc) * 8192;                     \
        _Float16* ld_ = &lw[buf][ldst];                                       \
        _Pragma("unroll")                                                     \
        for (int r = 0; r < 8; ++r)                                           \
            gload_lds16(gs_ + r * 512, ld_ + r * 512);                        \
    } while (0)

    f32x16 aH0[2], aH1[2], aM[2], aLL[2];
#pragma unroll
    for (int nt = 0; nt < 2; ++nt) {
        aH0[nt] = (f32x16)(0.f); aH1[nt] = (f32x16)(0.f);
        aM[nt]  = (f32x16)(0.f); aLL[nt] = (f32x16)(0.f);
    }
    float sum = 0.f, sumsq = 0.f;

    STAGEW(0, 0);
    __syncthreads();   // vmcnt(0) drain: chunk 0 staged

    for (int c = 0; c < 8; ++c) {
        if (c < 7) STAGEW(c + 1, (c + 1) & 1);
        const float* xp = xrow + c * 128;
        const _Float16* lwb = &lw[c & 1][0] + lane * 8;
#pragma unroll
        for (int t = 0; t < 8; ++t) {
            f32x4 x0 = *(const f32x4*)(xp + t * 16);
            f32x4 x1 = *(const f32x4*)(xp + t * 16 + 4);
            float xs[8] = {x0[0], x0[1], x0[2], x0[3], x1[0], x1[1], x1[2], x1[3]};
            f16x8 ahi, alo;
#pragma unroll
            for (int j = 0; j < 8; ++j) {
                float xv = xs[j];
                sum += xv;
                sumsq = fmaf(xv, xv, sumsq);
                _Float16 h = (_Float16)xv;
                ahi[j] = h;
                alo[j] = (_Float16)((xv - (float)h) * 2048.0f);
            }
            const _Float16* base = lwb + t * 1024;
#pragma unroll
            for (int nt = 0; nt < 2; ++nt) {
                f16x8 bh = *(const f16x8*)(base + nt * 512);
                f16x8 bl = *(const f16x8*)(base + nt * 512 + 8192);
                if (t & 1) aH1[nt] = mfma32(ahi, bh, aH1[nt]);
                else       aH0[nt] = mfma32(ahi, bh, aH0[nt]);
                aM[nt]  = mfma32(ahi, bl, aM[nt]);
                aM[nt]  = mfma32(alo, bh, aM[nt]);
                aLL[nt] = mfma32(alo, bl, aLL[nt]);
            }
        }
        __syncthreads();   // drains vmcnt(0): next chunk staged; cur buffer free
    }

    // LN1 stats: lane holds half of row (col)'s k-range; combine hi halves
    sum   += __shfl_xor(sum, 32);
    sumsq += __shfl_xor(sumsq, 32);
    float mu   = sum * (1.f / 1024.f);
    float var  = sumsq * (1.f / 1024.f) - mu * mu;
    float rstd = rsqrtf(var + LN_EPS);

    // per-bit constants: bit = nt*32 + col
    float uv[2], vv[2], g2v[2], b2v[2];
#pragma unroll
    for (int nt = 0; nt < 2; ++nt) {
        int bitc = nt * 32 + col;
        uv[nt] = u[bitc]; vv[nt] = v[bitc]; g2v[nt] = g2[bitc]; b2v[nt] = b2[bitc];
    }

    float ps0 = 0.f, ps1 = 0.f;
#pragma unroll
    for (int reg = 0; reg < 16; ++reg) {
        int r = (reg & 3) + 8 * (reg >> 2) + 4 * hi;   // row within wave, 0..31
        float mu_r = __shfl(mu, r);                    // lane r holds row r stats
        float rs_r = __shfl(rstd, r);
        float lg0, lg1;
        {
            float d0 = (aH0[0][reg] + aH1[0][reg])
                     + aM[0][reg] * (1.0f / 2048.0f)
                     + aLL[0][reg] * (1.0f / 4194304.0f);
            float d1 = (aH0[1][reg] + aH1[1][reg])
                     + aM[1][reg] * (1.0f / 2048.0f)
                     + aLL[1][reg] * (1.0f / 4194304.0f);
            lg0 = rs_r * d0 - rs_r * mu_r * uv[0] + vv[0];
            lg1 = rs_r * d1 - rs_r * mu_r * uv[1] + vv[1];
        }
        // LN2 over the 64 bits of row r: 2 nt x 32 lanes (within this hi-half)
        float s1 = lg0 + lg1;
        float s2 = lg0 * lg0 + lg1 * lg1;
#pragma unroll
        for (int m = 1; m <= 16; m <<= 1) {
            s1 += __shfl_xor(s1, m);
            s2 += __shfl_xor(s2, m);
        }
        float mean = s1 * (1.f / 64.f);
        float va   = s2 * (1.f / 64.f) - mean * mean;
        float rs2  = rsqrtf(va + LN_EPS);
        float o0 = (lg0 - mean) * rs2 * g2v[0] + b2v[0];
        float o1 = (lg1 - mean) * rs2 * g2v[1] + b2v[1];
        size_t row = (size_t)(row_base + r);
        L[row * 64 + col]      = o0;
        L[row * 64 + 32 + col] = o1;
        ps0 += o0;
        ps1 += o1;
    }

    // per-wave column partial sums over the wave's 32 rows; P layout [64][2048]
    ps0 += __shfl_xor(ps0, 32);
    ps1 += __shfl_xor(ps1, 32);
    if (hi == 0) {
        P[(size_t)col * 2048        + blockIdx.x * 4 + wid] = ps0;
        P[(size_t)(32 + col) * 2048 + blockIdx.x * 4 + wid] = ps1;
    }
#undef STAGEW
}

// ---------------- kernel 2: reduce column partials -> column means ----------------
__global__ void reduce_kernel(const float* __restrict__ P, float* __restrict__ cm) {
    int bit = blockIdx.x, t = threadIdx.x;
    float s = 0.f;
    for (int p = t; p < 2048; p += 256) s += P[(size_t)bit * 2048 + p];
    __shared__ float sh[256];
    sh[t] = s;
    __syncthreads();
    for (int off = 128; off > 0; off >>= 1) {
        if (t < off) sh[t] += sh[t + off];
        __syncthreads();
    }
    if (t == 0) cm[bit] = sh[0] * (1.f / (float)N_ROWS);
}

// ---------------- kernel 3: mean-center + fast sign-exact tanh + binarize ----------------
// tanh approx: |y|<0.5 -> odd polynomial (sign-exact by construction, |err|<4e-4);
// else 1 - 2/(e^{2y}+1). Threshold is 0.02.
__global__ void final_kernel(const float* __restrict__ L, const float* __restrict__ cm,
                             float* __restrict__ out) {
    __shared__ float cms[64];
    if (threadIdx.x < 64) cms[threadIdx.x] = cm[threadIdx.x];
    __syncthreads();
    const f32x4* L4 = (const f32x4*)L;
    f32x4* H4 = (f32x4*)out;
    f32x4* B4 = (f32x4*)(out + (size_t)N_ROWS * NBIT);
    int total = N_ROWS * NBIT / 4;
    for (int i = blockIdx.x * blockDim.x + threadIdx.x; i < total;
         i += gridDim.x * blockDim.x) {
        f32x4 x = L4[i];
        int bb = (i & 15) * 4;
        f32x4 h, bo;
#pragma unroll
        for (int j = 0; j < 4; ++j) {
            float y  = 0.5f * (x[j] - cms[bb + j]);
            float y2 = y * y;
            float poly = y * fmaf(y2, fmaf(y2, 2.f / 15.f, -1.f / 3.f), 1.f);
            float e  = __expf(2.f * y);
            float ef = 1.f - 2.f / (e + 1.f);
            float hv = (fabsf(y) < 0.5f) ? poly : ef;
            h[j]  = hv;
            bo[j] = hv >= 0.f ? 1.f : -1.f;
        }
        __builtin_nontemporal_store(h, &H4[i]);
        __builtin_nontemporal_store(bo, &B4[i]);
    }
}

extern "C" void kernel_launch(void* const* d_in, const int* in_sizes, int n_in,
                              void* d_out, int out_size, void* d_ws, size_t ws_size,
                              hipStream_t stream) {
    (void)in_sizes; (void)n_in; (void)out_size; (void)ws_size;
    const float* X  = (const float*)d_in[0];
    const float* W  = (const float*)d_in[1];
    const float* bb = (const float*)d_in[2];
    const float* g1 = (const float*)d_in[3];
    const float* b1 = (const float*)d_in[4];
    const float* g2 = (const float*)d_in[5];
    const float* b2 = (const float*)d_in[6];

    char* ws = (char*)d_ws;
    _Float16* whi = (_Float16*)ws;                 // 128 KiB
    _Float16* wlo = (_Float16*)(ws + 131072);      // 128 KiB
    float* u  = (float*)(ws + 262144);             // 256 B
    float* v  = (float*)(ws + 266240);             // 256 B
    float* P  = (float*)(ws + 270336);             // 512 KiB (64*2048*4)
    float* cm = (float*)(ws + 270336 + 64 * 2048 * 4);

    float* out = (float*)d_out;
    float* L   = out + (size_t)N_ROWS * NBIT;      // reuse B-half of d_out as logit scratch

    prep_kernel<<<64, 256, 0, stream>>>(W, bb, g1, b1, whi, wlo, u, v);
    main_kernel<<<512, 256, 0, stream>>>(X, whi, wlo, u, v, g2, b2, L, P);
    reduce_kernel<<<64, 256, 0, stream>>>(P, cm);
    final_kernel<<<2048, 256, 0, stream>>>(L, cm, out);
}